// Round 2
// baseline (291.516 us; speedup 1.0000x reference)
//
#include <hip/hip_runtime.h>
#include <stdint.h>

#define C_DIM  256
#define F_DIM  256
#define HW     4096   // 64*64
#define JT     64     // hw tile width per block
#define NCHUNK 8      // K chunks of 32 c each

typedef __attribute__((ext_vector_type(8))) short   bf16x8;
typedef __attribute__((ext_vector_type(4))) float   floatx4;

__device__ __forceinline__ unsigned short f32_to_bf16(float f) {
    union { float f; unsigned int u; } v; v.f = f;
    unsigned int u = v.u;
    return (unsigned short)((u + 0x7FFFu + ((u >> 16) & 1u)) >> 16);
}

// ---------------- prep: colsum + pack in one kernel, 16 blocks ----------------
// Block ftile handles f in [16*ftile, 16*ftile+16).
// apack flat ((ftile*8 + kiter)*64 + lane)*8 + i holds
//   A[f = 16*ftile + (lane&15)][c = 32*kiter + (lane>>4)*8 + i]  (bf16)
__global__ void prep_kernel(const float* __restrict__ b,
                            unsigned short* __restrict__ apack) {
    __shared__ float part[16][17];
    __shared__ float inv_s[16];
    const int t     = threadIdx.x;
    const int ftile = blockIdx.x;
    const int f0    = ftile * 16;

    const int fl = t & 15;
    const int cg = t >> 4;
    float s = 0.f;
#pragma unroll
    for (int k = 0; k < 16; ++k) {
        float v = b[(cg + 16 * k) * F_DIM + f0 + fl];
        s += v * v;
    }
    part[cg][fl] = s;
    __syncthreads();
    if (t < 16) {
        float acc = 0.f;
#pragma unroll
        for (int g = 0; g < 16; ++g) acc += part[g][t];
        inv_s[t] = 1.0f / acc;
    }
    __syncthreads();

#pragma unroll
    for (int e = t; e < 512; e += 256) {
        const int kiter = e >> 6;
        const int lane  = e & 63;
        const int f     = f0 + (lane & 15);
        const int c0    = kiter * 32 + ((lane >> 4) << 3);
        const float inv = inv_s[lane & 15];
        bf16x8 v;
#pragma unroll
        for (int i = 0; i < 8; ++i) {
            float w = b[(c0 + i) * F_DIM + f];
            v[i] = (short)f32_to_bf16(w * w * inv);
        }
        *(bf16x8*)(apack + ((size_t)(ftile * 8 + kiter) * 64 + lane) * 8) = v;
    }
}

// ---------------- main fused kernel: NO LDS, NO BARRIERS ----------------
// out[b,f,hw] = log( sum_c exp(x[b,c,hw]) * p[c,f] )  (x ~ N(0,1): exp safe,
// all-positive sum -> no max subtraction needed).
//
// Block = 256 threads = 4 independent waves; block covers (batch, 64-wide hw
// tile) x all 256 f. Wave wv: f-half fg = wv&1 (f-tiles fg*8..fg*8+7),
// j-quarter jg = wv>>1 (j = jg*32 .. +31, i.e. 2 MFMA j-tiles).
//
// B-fragments are loaded DIRECTLY from global x in MFMA lane layout:
//   lane l, reg q -> x[batch, c = ck*32 + (l>>4)*8 + q, hw0 + j]
// i.e. each global_load_dword is 4 coalesced 64 B segments (16 lanes x 4 B).
// The two waves sharing a j-quarter (fg=0,1) read the same lines -> L1/L2 hit;
// x is read 2x total from cache instead of staged once through LDS. exp() is
// applied in-register, then packed to bf16 for the MFMA B operand.
//
// x loads are register-prefetched one chunk ahead (16 f32/lane) so L2 latency
// hides under the current chunk's exp+cvt+MFMA. No synchronization anywhere:
// every wave is an independent pipeline (vs. the old 8-wave barrier convoy at
// 2 blocks/CU, which left all pipes <30% busy).
__global__ __launch_bounds__(256, 4)
void mixture_kernel(const float* __restrict__ x,
                    const unsigned short* __restrict__ apack,
                    float* __restrict__ out) {
    const int t     = threadIdx.x;
    const int wv    = t >> 6;        // 0..3
    const int lane  = t & 63;
    const int llo   = lane & 15;
    const int lhi   = lane >> 4;
    const int fg    = wv & 1;        // f half
    const int jg    = wv >> 1;       // j quarter (32 cols)
    const int batch = blockIdx.x >> 6;
    const int hw0   = (blockIdx.x & 63) * JT;

    // per-lane base: x[batch, c = lhi*8, hw0 + jg*32 + llo]
    const float* xl = x + (size_t)batch * C_DIM * HW
                        + (size_t)(lhi * 8) * HW + hw0 + jg * 32 + llo;

    const bf16x8* ap = (const bf16x8*)apack;

    floatx4 acc[8][2];
#pragma unroll
    for (int ft = 0; ft < 8; ++ft)
#pragma unroll
        for (int jj = 0; jj < 2; ++jj)
            acc[ft][jj] = (floatx4){0.f, 0.f, 0.f, 0.f};

    // prologue: load chunk 0 raw x into registers
    float xc[2][8];
#pragma unroll
    for (int jj = 0; jj < 2; ++jj)
#pragma unroll
        for (int q = 0; q < 8; ++q)
            xc[jj][q] = xl[(size_t)q * HW + jj * 16];

#pragma unroll
    for (int ck = 0; ck < NCHUNK; ++ck) {
        // prefetch chunk ck+1 (independent of everything below)
        float xn[2][8];
        if (ck < NCHUNK - 1) {
#pragma unroll
            for (int jj = 0; jj < 2; ++jj)
#pragma unroll
                for (int q = 0; q < 8; ++q)
                    xn[jj][q] = xl[(size_t)((ck + 1) * 32 + q) * HW + jj * 16];
        }

        // exp + pack chunk ck into the two B fragments (reg q <-> c-octet elem)
        bf16x8 bfr[2];
#pragma unroll
        for (int jj = 0; jj < 2; ++jj)
#pragma unroll
            for (int q = 0; q < 8; ++q)
                bfr[jj][q] = (short)f32_to_bf16(__expf(xc[jj][q]));

        // MFMA: 8 f-tiles x 2 j-tiles, afrag streamed from L2-hot apack
#pragma unroll
        for (int ft = 0; ft < 8; ++ft) {
            bf16x8 af = ap[((size_t)(fg * 8 + ft) * 8 + ck) * 64 + lane];
            acc[ft][0] = __builtin_amdgcn_mfma_f32_16x16x32_bf16(
                af, bfr[0], acc[ft][0], 0, 0, 0);
            acc[ft][1] = __builtin_amdgcn_mfma_f32_16x16x32_bf16(
                af, bfr[1], acc[ft][1], 0, 0, 0);
        }

        if (ck < NCHUNK - 1) {
#pragma unroll
            for (int jj = 0; jj < 2; ++jj)
#pragma unroll
                for (int q = 0; q < 8; ++q)
                    xc[jj][q] = xn[jj][q];   // register rename, free
        }
    }

    // ---- Epilogue: out[batch, f, hw0 + jg*32 + jj*16 + llo] = log(acc) ----
    // C/D layout: col(n) = lane&15 = j, row(m) = lhi*4 + r = f within tile.
    float* ob = out + (size_t)batch * F_DIM * HW + hw0 + jg * 32 + llo;
#pragma unroll
    for (int ft = 0; ft < 8; ++ft) {
        const int fbase = (fg * 8 + ft) * 16 + lhi * 4;
#pragma unroll
        for (int r = 0; r < 4; ++r) {
            float* orow = ob + (size_t)(fbase + r) * HW;
#pragma unroll
            for (int jj = 0; jj < 2; ++jj)
                orow[jj * 16] = __logf(acc[ft][jj][r]);
        }
    }
}

extern "C" void kernel_launch(void* const* d_in, const int* in_sizes, int n_in,
                              void* d_out, int out_size, void* d_ws, size_t ws_size,
                              hipStream_t stream) {
    const float* x      = (const float*)d_in[0];   // (32,256,64,64) f32
    const float* biases = (const float*)d_in[1];   // (1,1,256,256) f32
    float* out = (float*)d_out;                    // (32,256,64,64) f32

    unsigned short* apack = (unsigned short*)d_ws;  // 128 KiB

    prep_kernel<<<16, 256, 0, stream>>>(biases, apack);
    mixture_kernel<<<2048, 256, 0, stream>>>(x, apack, out);
}

// Round 3
// 253.410 us; speedup vs baseline: 1.1504x; 1.1504x over previous
//
#include <hip/hip_runtime.h>
#include <stdint.h>

#define C_DIM  256
#define F_DIM  256
#define HW     4096   // 64*64
#define TW     128    // hw tile width per block
#define NCHUNK 8      // K chunks of 32 c each
#define ETP    40     // et row pitch in bf16 (80 B = odd # of 16B blocks)

typedef __attribute__((ext_vector_type(8))) short   bf16x8;
typedef __attribute__((ext_vector_type(4))) float   floatx4;

__device__ __forceinline__ unsigned short f32_to_bf16(float f) {
    union { float f; unsigned int u; } v; v.f = f;
    unsigned int u = v.u;
    return (unsigned short)((u + 0x7FFFu + ((u >> 16) & 1u)) >> 16);
}

// async global->LDS, 16 B per lane (lds dst = wave-uniform base + lane*16)
__device__ __forceinline__ void async_load16(const float* g, float* l) {
    __builtin_amdgcn_global_load_lds(
        (const __attribute__((address_space(1))) void*)g,
        (__attribute__((address_space(3))) void*)l, 16, 0, 0);
}

// ---------------- prep: colsum + pack in one kernel, 16 blocks ----------------
// Block ftile handles f in [16*ftile, 16*ftile+16).
// apack flat ((ftile*8 + kiter)*64 + lane)*8 + i holds
//   A[f = 16*ftile + (lane&15)][c = 32*kiter + (lane>>4)*8 + i]  (bf16)
__global__ void prep_kernel(const float* __restrict__ b,
                            unsigned short* __restrict__ apack) {
    __shared__ float part[16][17];
    __shared__ float inv_s[16];
    const int t     = threadIdx.x;
    const int ftile = blockIdx.x;
    const int f0    = ftile * 16;

    const int fl = t & 15;
    const int cg = t >> 4;
    float s = 0.f;
#pragma unroll
    for (int k = 0; k < 16; ++k) {
        float v = b[(cg + 16 * k) * F_DIM + f0 + fl];
        s += v * v;
    }
    part[cg][fl] = s;
    __syncthreads();
    if (t < 16) {
        float acc = 0.f;
#pragma unroll
        for (int g = 0; g < 16; ++g) acc += part[g][t];
        inv_s[t] = 1.0f / acc;
    }
    __syncthreads();

#pragma unroll
    for (int e = t; e < 512; e += 256) {
        const int kiter = e >> 6;
        const int lane  = e & 63;
        const int f     = f0 + (lane & 15);
        const int c0    = kiter * 32 + ((lane >> 4) << 3);
        const float inv = inv_s[lane & 15];
        bf16x8 v;
#pragma unroll
        for (int i = 0; i < 8; ++i) {
            float w = b[(c0 + i) * F_DIM + f];
            v[i] = (short)f32_to_bf16(w * w * inv);
        }
        *(bf16x8*)(apack + ((size_t)(ftile * 8 + kiter) * 64 + lane) * 8) = v;
    }
}

// ---------------- main fused kernel ----------------
// out[b,f,hw] = log( sum_c exp(x[b,c,hw]) * p[c,f] )  (x ~ N(0,1): exp safe,
// all-positive sum -> no max subtraction needed).
//
// Block = (batch, 128-wide hw tile), 512 threads = 8 waves, 2 blocks/CU.
// Pipeline (verified identical perf 2-barrier/1-deep vs 1-barrier/2-deep):
// ONE barrier per K-chunk, sbuf 3-deep, DMA 2 chunks ahead, counted vmcnt.
//
// R3 change — store path only (theory: 84 us plateau = DRAM write efficiency,
// not wave latency; R2 showed finer access granularity REDUCES effective BW):
//  * MFMA operands swapped: mfma(bfrag, afrag). A/B lane layouts are
//    identical (k = (lane>>4)*8+reg, m/n = lane&15), so D comes out
//    transposed: lane holds D[hw_local = (lane>>4)*4 + r][f_local = lane&15]
//    -> 4 CONSECUTIVE hw per lane at fixed f.
//  * Epilogue: one dwordx4 non-temporal store per (f-tile, j-tile) -- 16 B
//    per lane, 4x fewer store instrs, full 64 B segments, and `nt` bypasses
//    L2 so the 131 MB output stream reaches DRAM in program order (sequential
//    per row) instead of random L2-eviction order, and stops fighting the x
//    DMA stream for L2 capacity.
__global__ __launch_bounds__(512, 4)
void mixture_kernel(const float* __restrict__ x,
                    const unsigned short* __restrict__ apack,
                    float* __restrict__ out) {
    __shared__ __align__(16) float          sbuf[3][32][TW];   // 48 KiB
    __shared__ __align__(16) unsigned short et[2][TW][ETP];    // 20 KiB

    const int t     = threadIdx.x;
    const int wv    = t >> 6;        // 0..7
    const int lane  = t & 63;
    const int batch = blockIdx.x >> 5;
    const int hw0   = (blockIdx.x & 31) * TW;

    const float* xb = x + (size_t)batch * C_DIM * HW + hw0;

    // ---- DMA one chunk: wave wv loads rows 4wv..4wv+3; 2 rows per instr ----
    // (lanes 0-31 -> row rr, lanes 32-63 -> row rr+1; 1 KiB contiguous LDS)
#define DMA_CHUNK(ck, buf)                                                      \
    {                                                                           \
        _Pragma("unroll")                                                       \
        for (int r = 0; r < 2; ++r) {                                           \
            const int rr = 4 * wv + 2 * r;                                      \
            const float* g = xb + (size_t)((ck) * 32 + rr + (lane >> 5)) * HW   \
                                + (lane & 31) * 4;                              \
            async_load16(g, &sbuf[buf][rr][0]);                                 \
        }                                                                       \
    }

    // ---- transpose one chunk: sbuf[sb][c][j] -> exp -> bf16 -> et[eb][j][c] ----
#define TRANSPOSE_CHUNK(sb, eb)                                                 \
    {                                                                           \
        float xv[8];                                                            \
        _Pragma("unroll")                                                       \
        for (int q = 0; q < 8; ++q) xv[q] = sbuf[sb][cg * 8 + q][j];            \
        bf16x8 v;                                                               \
        _Pragma("unroll")                                                       \
        for (int q = 0; q < 8; ++q) v[q] = (short)f32_to_bf16(__expf(xv[q]));   \
        *(bf16x8*)&et[eb][j][cg * 8] = v;                                       \
    }

    const int llo = lane & 15;
    const int lhi = lane >> 4;
    const int j   = t & 127;   // hw column for transpose
    const int cg  = t >> 7;    // c-octet group for transpose

    floatx4 acc[2][8];
#pragma unroll
    for (int a = 0; a < 2; ++a)
#pragma unroll
        for (int jt = 0; jt < 8; ++jt)
            acc[a][jt] = (floatx4){0.f, 0.f, 0.f, 0.f};

    const bf16x8* ap = (const bf16x8*)apack;

    // ---- prologue: fill pipeline 2 deep, transpose chunk 0 ----
    DMA_CHUNK(0, 0);
    asm volatile("" ::: "memory");   // pin afrag(0) loads after DMA(0) issue
    bf16x8 a0c = ap[((2 * wv + 0) * 8 + 0) * 64 + lane];
    bf16x8 a1c = ap[((2 * wv + 1) * 8 + 0) * 64 + lane];
    DMA_CHUNK(1, 1);
    // drain DMA(0) (4 younger vmem allowed: afrag(0) + DMA(1), any order)
    asm volatile("s_waitcnt vmcnt(4)\n\ts_barrier" ::: "memory");
    TRANSPOSE_CHUNK(0, 0);

#pragma unroll
    for (int i = 0; i < NCHUNK; ++i) {
        const int eb = i & 1;

        // afrag loads for chunk i+1 (consumed next interval)
        bf16x8 a0n, a1n;
        if (i < NCHUNK - 1) {
            a0n = ap[((2 * wv + 0) * 8 + (i + 1)) * 64 + lane];
            a1n = ap[((2 * wv + 1) * 8 + (i + 1)) * 64 + lane];
        }
        // DMA chunk i+2 (needed at barrier i+1 -> ~2 compute phases in flight)
        if (i < NCHUNK - 2) DMA_CHUNK(i + 2, (i + 2) % 3);

        // single barrier per chunk: drain DMA(i+1)+afrag(i) (vmem) and all
        // prior-interval LDS ops; leave this interval's 4 vmem ops in flight
        if (i < NCHUNK - 2)
            asm volatile("s_waitcnt vmcnt(4) lgkmcnt(0)\n\ts_barrier" ::: "memory");
        else if (i == NCHUNK - 2)
            asm volatile("s_waitcnt vmcnt(2) lgkmcnt(0)\n\ts_barrier" ::: "memory");
        else
            asm volatile("s_waitcnt vmcnt(0) lgkmcnt(0)\n\ts_barrier" ::: "memory");

        // ---- MFMA chunk i (et[eb]), SWAPPED operands: D = E^T x P  ----
        // acc[a][jt] tile: rows = hw (jt*16 ..), cols = f ((2wv+a)*16 ..)
#pragma unroll
        for (int jt = 0; jt < 8; ++jt) {
            bf16x8 bfrag = *(const bf16x8*)&et[eb][jt * 16 + llo][lhi * 8];
            acc[0][jt] = __builtin_amdgcn_mfma_f32_16x16x32_bf16(
                bfrag, a0c, acc[0][jt], 0, 0, 0);
            acc[1][jt] = __builtin_amdgcn_mfma_f32_16x16x32_bf16(
                bfrag, a1c, acc[1][jt], 0, 0, 0);
        }

        // ---- transpose chunk i+1 into the other et buffer (VALU/LDS pipes,
        //      overlaps the MFMA above; hazards resolved at next barrier) ----
        if (i < NCHUNK - 1) TRANSPOSE_CHUNK((i + 1) % 3, eb ^ 1);

        if (i < NCHUNK - 1) { a0c = a0n; a1c = a1n; }
    }

    // ---- Epilogue: lane holds out[f = f0+llo][hw = hw0 + jt*16 + lhi*4 + r],
    //      r=0..3 consecutive -> one dwordx4 nt store per (a, jt) ----
    float* ob = out + (size_t)batch * F_DIM * HW + hw0;
#pragma unroll
    for (int a = 0; a < 2; ++a) {
        const int f = (2 * wv + a) * 16 + llo;
        float* orow = ob + (size_t)f * HW + lhi * 4;
#pragma unroll
        for (int jt = 0; jt < 8; ++jt) {
            floatx4 v;
#pragma unroll
            for (int r = 0; r < 4; ++r) v[r] = __logf(acc[a][jt][r]);
            __builtin_nontemporal_store(v, (floatx4*)(orow + jt * 16));
        }
    }
}

extern "C" void kernel_launch(void* const* d_in, const int* in_sizes, int n_in,
                              void* d_out, int out_size, void* d_ws, size_t ws_size,
                              hipStream_t stream) {
    const float* x      = (const float*)d_in[0];   // (32,256,64,64) f32
    const float* biases = (const float*)d_in[1];   // (1,1,256,256) f32
    float* out = (float*)d_out;                    // (32,256,64,64) f32

    unsigned short* apack = (unsigned short*)d_ws;  // 128 KiB

    prep_kernel<<<16, 256, 0, stream>>>(biases, apack);
    mixture_kernel<<<1024, 512, 0, stream>>>(x, apack, out);
}

// Round 4
// 250.363 us; speedup vs baseline: 1.1644x; 1.0122x over previous
//
#include <hip/hip_runtime.h>
#include <stdint.h>

#define C_DIM  256
#define F_DIM  256
#define HW     4096   // 64*64
#define TW     256    // hw tile width per block (1 KiB rows -> DRAM run length)
#define FB     128    // f per block (2 f-half blocks share one x slice via L2)
#define CCH    16     // c per staging chunk (16 rows x 1 KiB = 16 KiB)
#define NH     16     // staging half-rounds (16 x 16c = 256 c)
#define ETP    40     // et row pitch in bf16 (80 B, same bank profile as before)

typedef __attribute__((ext_vector_type(8))) short   bf16x8;
typedef __attribute__((ext_vector_type(4))) float   floatx4;

__device__ __forceinline__ unsigned short f32_to_bf16(float f) {
    union { float f; unsigned int u; } v; v.f = f;
    unsigned int u = v.u;
    return (unsigned short)((u + 0x7FFFu + ((u >> 16) & 1u)) >> 16);
}

// async global->LDS, 16 B per lane (lds dst = wave-uniform base + lane*16)
__device__ __forceinline__ void async_load16(const float* g, float* l) {
    __builtin_amdgcn_global_load_lds(
        (const __attribute__((address_space(1))) void*)g,
        (__attribute__((address_space(3))) void*)l, 16, 0, 0);
}

// ---------------- prep: colsum + pack in one kernel, 16 blocks ----------------
// apack flat ((ftile*8 + kiter)*64 + lane)*8 + i holds
//   A[f = 16*ftile + (lane&15)][c = 32*kiter + (lane>>4)*8 + i]  (bf16)
__global__ void prep_kernel(const float* __restrict__ b,
                            unsigned short* __restrict__ apack) {
    __shared__ float part[16][17];
    __shared__ float inv_s[16];
    const int t     = threadIdx.x;
    const int ftile = blockIdx.x;
    const int f0    = ftile * 16;

    const int fl = t & 15;
    const int cg = t >> 4;
    float s = 0.f;
#pragma unroll
    for (int k = 0; k < 16; ++k) {
        float v = b[(cg + 16 * k) * F_DIM + f0 + fl];
        s += v * v;
    }
    part[cg][fl] = s;
    __syncthreads();
    if (t < 16) {
        float acc = 0.f;
#pragma unroll
        for (int g = 0; g < 16; ++g) acc += part[g][t];
        inv_s[t] = 1.0f / acc;
    }
    __syncthreads();

#pragma unroll
    for (int e = t; e < 512; e += 256) {
        const int kiter = e >> 6;
        const int lane  = e & 63;
        const int f     = f0 + (lane & 15);
        const int c0    = kiter * 32 + ((lane >> 4) << 3);
        const float inv = inv_s[lane & 15];
        bf16x8 v;
#pragma unroll
        for (int i = 0; i < 8; ++i) {
            float w = b[(c0 + i) * F_DIM + f];
            v[i] = (short)f32_to_bf16(w * w * inv);
        }
        *(bf16x8*)(apack + ((size_t)(ftile * 8 + kiter) * 64 + lane) * 8) = v;
    }
}

// ---------------- main fused kernel ----------------
// out[b,f,hw] = log( sum_c exp(x[b,c,hw]) * p[c,f] )  (x ~ N(0,1): exp safe).
//
// R4: tile reshape for DRAM run length. Block = (batch, f-half of 128,
// 256-wide hw tile); 512 threads = 8 waves, 2 blocks/CU (68 KiB LDS).
//  * x DMA: one instruction = one full 1 KiB contiguous row-slice.
//  * out: each f row gets a 1 KiB contiguous run (vs 512 B before).
//  * sibling f-half block (bid +16, same XCD mod 8) re-reads the x slice
//    L2-hot; HBM-side read traffic unchanged.
// K-machinery: 16 half-rounds of 16 c; sbuf 3-deep (WAR-safe for
// DMA-issued-before-barrier); SINGLE et buffer (every half-round barrier
// carries lgkmcnt(0), so MFMA r completes before transpose of round r+1
// overwrites et). MFMA fires every odd half-round (K=32). vmcnt counted,
// never full-drained mid-loop: even h -> vmcnt(2), odd h -> vmcnt(4).
__global__ __launch_bounds__(512, 4)
void mixture_kernel(const float* __restrict__ x,
                    const unsigned short* __restrict__ apack,
                    float* __restrict__ out) {
    __shared__ __align__(16) float          sbuf[3][CCH][TW];  // 48 KiB
    __shared__ __align__(16) unsigned short et[TW][ETP];       // 20 KiB

    const int t     = threadIdx.x;
    const int wv    = t >> 6;        // 0..7
    const int lane  = t & 63;
    const int batch = blockIdx.x >> 5;
    const int fh    = (blockIdx.x >> 4) & 1;   // f half (0..1)
    const int tile  = blockIdx.x & 15;         // hw tile (0..15)
    const int hw0   = tile * TW;
    const int f0    = fh * FB;

    const float* xb = x + (size_t)batch * C_DIM * HW + hw0;

    // ---- DMA one 16c chunk: wave wv loads rows 2wv, 2wv+1 (1 KiB each) ----
#define DMA_CHUNK(ck, slot)                                                     \
    {                                                                           \
        _Pragma("unroll")                                                       \
        for (int r = 0; r < 2; ++r) {                                           \
            const int rr = 2 * wv + r;                                          \
            const float* g = xb + (size_t)((ck) * CCH + rr) * HW + lane * 4;    \
            async_load16(g, &sbuf[slot][rr][0]);                                \
        }                                                                       \
    }

    // ---- transpose one 16c chunk into et half: sbuf[slot][c][j] -> et[j][c] --
    // 512 threads x 8 elems = 16 c x 256 j. j = t&255 (lane-contiguous reads).
#define TRANSPOSE_CHUNK(slot, half)                                             \
    {                                                                           \
        float xv[8];                                                            \
        _Pragma("unroll")                                                       \
        for (int q = 0; q < 8; ++q) xv[q] = sbuf[slot][cg * 8 + q][j];          \
        bf16x8 v;                                                               \
        _Pragma("unroll")                                                       \
        for (int q = 0; q < 8; ++q) v[q] = (short)f32_to_bf16(__expf(xv[q]));   \
        *(bf16x8*)&et[j][(half) * 16 + cg * 8] = v;                             \
    }

    const int llo = lane & 15;
    const int lhi = lane >> 4;
    const int j   = t & 255;   // hw column for transpose
    const int cg  = t >> 8;    // c-octet group (0..1)

    // wave tile: fg = wv&3 -> local f-tiles {2fg, 2fg+1}; jh = wv>>2 -> j-tiles
    // jh*8 .. jh*8+7 (16 cols each).
    const int fg = wv & 3;
    const int jh = wv >> 2;

    floatx4 acc[2][8];
#pragma unroll
    for (int a = 0; a < 2; ++a)
#pragma unroll
        for (int jt = 0; jt < 8; ++jt)
            acc[a][jt] = (floatx4){0.f, 0.f, 0.f, 0.f};

    const bf16x8* ap = (const bf16x8*)apack;
    // global f-tile indices for this wave
    const int ft0 = fh * 8 + 2 * fg;

    // ---- prologue: afrag(0), DMA(0) ----
    bf16x8 a0c = ap[((size_t)(ft0 + 0) * 8 + 0) * 64 + lane];
    bf16x8 a1c = ap[((size_t)(ft0 + 1) * 8 + 0) * 64 + lane];
    asm volatile("" ::: "memory");
    DMA_CHUNK(0, 0);

#pragma unroll
    for (int h = 0; h < NH; ++h) {
        const int r   = h >> 1;
        const int odd = h & 1;

        // afrag loads for round r+1 (issued at odd h, consumed at h+2)
        bf16x8 a0n, a1n;
        if (odd && r + 1 < 8) {
            a0n = ap[((size_t)(ft0 + 0) * 8 + (r + 1)) * 64 + lane];
            a1n = ap[((size_t)(ft0 + 1) * 8 + (r + 1)) * 64 + lane];
        }
        // DMA next chunk (slot (h+1)%3: its tenant chunk h-2 was transposed at
        // h-2 and those ds_reads drained at the top barrier of h-1 -> WAR-safe)
        if (h + 1 < NH) DMA_CHUNK(h + 1, (h + 1) % 3);

        // top barrier: drain DMA(h) (+ anything older, incl. afrag(r));
        // leave this half-round's vmem (DMA(h+1) [+ afrag(r+1) if odd]) in
        // flight. lgkmcnt(0) covers all prior LDS ops (et/sbuf WAR+RAW).
        if (h + 1 < NH) {
            if (odd) asm volatile("s_waitcnt vmcnt(4) lgkmcnt(0)\n\ts_barrier" ::: "memory");
            else     asm volatile("s_waitcnt vmcnt(2) lgkmcnt(0)\n\ts_barrier" ::: "memory");
        } else {
            asm volatile("s_waitcnt vmcnt(0) lgkmcnt(0)\n\ts_barrier" ::: "memory");
        }

        // transpose chunk h into et half (odd = upper 16 c of this K=32 round)
        TRANSPOSE_CHUNK(h % 3, odd);

        if (odd) {
            // et round r complete across all threads -> MFMA
            asm volatile("s_waitcnt lgkmcnt(0)\n\ts_barrier" ::: "memory");
            // D = E^T x P (swapped operands): lane holds
            // D[hw_local = lhi*4 + rr][f_local = llo]
#pragma unroll
            for (int jt = 0; jt < 8; ++jt) {
                bf16x8 bfrag = *(const bf16x8*)&et[(jh * 8 + jt) * 16 + llo][lhi * 8];
                acc[0][jt] = __builtin_amdgcn_mfma_f32_16x16x32_bf16(
                    bfrag, a0c, acc[0][jt], 0, 0, 0);
                acc[1][jt] = __builtin_amdgcn_mfma_f32_16x16x32_bf16(
                    bfrag, a1c, acc[1][jt], 0, 0, 0);
            }
            if (r + 1 < 8) { a0c = a0n; a1c = a1n; }
        }
    }

    // ---- Epilogue: lane holds out[f = f0 + (2fg+a)*16 + llo]
    //      [hw = hw0 + (jh*8+jt)*16 + lhi*4 + rr], rr consecutive -> dwordx4 ----
    float* ob = out + (size_t)batch * F_DIM * HW + hw0;
#pragma unroll
    for (int a = 0; a < 2; ++a) {
        const int f = f0 + (2 * fg + a) * 16 + llo;
        float* orow = ob + (size_t)f * HW + jh * 128 + lhi * 4;
#pragma unroll
        for (int jt = 0; jt < 8; ++jt) {
            floatx4 v;
#pragma unroll
            for (int rr = 0; rr < 4; ++rr) v[rr] = __logf(acc[a][jt][rr]);
            *(floatx4*)(orow + jt * 16) = v;
        }
    }
}

extern "C" void kernel_launch(void* const* d_in, const int* in_sizes, int n_in,
                              void* d_out, int out_size, void* d_ws, size_t ws_size,
                              hipStream_t stream) {
    const float* x      = (const float*)d_in[0];   // (32,256,64,64) f32
    const float* biases = (const float*)d_in[1];   // (1,1,256,256) f32
    float* out = (float*)d_out;                    // (32,256,64,64) f32

    unsigned short* apack = (unsigned short*)d_ws;  // 128 KiB

    prep_kernel<<<16, 256, 0, stream>>>(biases, apack);
    mixture_kernel<<<1024, 512, 0, stream>>>(x, apack, out);
}